// Round 10
// baseline (1373.171 us; speedup 1.0000x reference)
//
#include <hip/hip_runtime.h>
#include <hip/hip_cooperative_groups.h>

#define N_NODES   50000
#define N_EDGES   600000
#define F         128
#define N_GRAPHS  512
#define MROWS     32          // rows per block in layer kernel
#define ASTRIDE   264         // Ahi LDS row stride in shorts (16B-aligned)
#define ALSTRIDE  136         // Alo LDS row stride in shorts (agg half only)
#define NB_SCAN   196         // ceil(N_NODES/256)

typedef short          short8   __attribute__((ext_vector_type(8)));
typedef float          f32x4    __attribute__((ext_vector_type(4)));
typedef unsigned int   uint4_t  __attribute__((ext_vector_type(4)));

__device__ __forceinline__ void split_bf16(float v, short& hi, short& lo) {
    unsigned u  = __float_as_uint(v);
    unsigned hb = u & 0xFFFF0000u;
    hi = (short)(u >> 16);
    float rem = v - __uint_as_float(hb);
    lo = (short)(__float_as_uint(rem) >> 16);
}

// f32 -> bf16 round-to-nearest-even
__device__ __forceinline__ unsigned short f2bf_rne(float f) {
    unsigned u = __float_as_uint(f);
    u += 0x7FFFu + ((u >> 16) & 1u);
    return (unsigned short)(u >> 16);
}

__device__ __forceinline__ void wsplit_one(
    int gt,
    const float* __restrict__ Wl0, const float* __restrict__ Wr0,
    const float* __restrict__ Wl1, const float* __restrict__ Wr1,
    const float* __restrict__ Wl2, const float* __restrict__ Wr2,
    const float* __restrict__ Wl3, const float* __restrict__ Wr3,
    short* __restrict__ wtbase)
{
    int l = gt >> 15;
    int t = gt & 32767;
    const float* Wl; const float* Wr;
    switch (l) {
        case 0:  Wl = Wl0; Wr = Wr0; break;
        case 1:  Wl = Wl1; Wr = Wr1; break;
        case 2:  Wl = Wl2; Wr = Wr2; break;
        default: Wl = Wl3; Wr = Wr3; break;
    }
    int n = t >> 8, k = t & 255;
    float w = (k < F) ? Wl[k * F + n] : Wr[(k - F) * F + n];
    short h, lo;
    split_bf16(w, h, lo);
    short* hi_plane = wtbase + (size_t)l * 65536;
    hi_plane[t]         = h;
    hi_plane[32768 + t] = lo;
}

__device__ __forceinline__ void x2bf_one(int i, const float* __restrict__ x,
                                         unsigned short* __restrict__ xb) {
    float4 a = ((const float4*)x)[2 * i];
    float4 b = ((const float4*)x)[2 * i + 1];
    short8 o;
    o[0] = (short)f2bf_rne(a.x); o[1] = (short)f2bf_rne(a.y);
    o[2] = (short)f2bf_rne(a.z); o[3] = (short)f2bf_rne(a.w);
    o[4] = (short)f2bf_rne(b.x); o[5] = (short)f2bf_rne(b.y);
    o[6] = (short)f2bf_rne(b.z); o[7] = (short)f2bf_rne(b.w);
    ((short8*)xb)[i] = o;
}

// ---------------------------------------------------------------------------
// Cooperative fused prep: zero+convert+Wsplit -> degree -> scan -> fill.
// Launch with as many co-resident 256-thread blocks as the device allows.
__global__ __launch_bounds__(256) void prep_kernel(
    const int* __restrict__ src, const int* __restrict__ dst,
    const float* __restrict__ x,
    const float* __restrict__ Wl0, const float* __restrict__ Wr0,
    const float* __restrict__ Wl1, const float* __restrict__ Wr1,
    const float* __restrict__ Wl2, const float* __restrict__ Wr2,
    const float* __restrict__ Wl3, const float* __restrict__ Wr3,
    short* __restrict__ wtbase, unsigned short* __restrict__ xb,
    int* __restrict__ deg, int* __restrict__ bsum,
    int* __restrict__ row_start, int* __restrict__ cursor,
    float* __restrict__ inv_deg, int* __restrict__ eidx)
{
    cooperative_groups::grid_group grid = cooperative_groups::this_grid();
    __shared__ int s[256];
    const int t    = threadIdx.x;
    const int gid  = blockIdx.x * 256 + t;
    const int nthr = gridDim.x * 256;

    // ---- phase A: zero deg, x->bf16, W split ----
    for (int i = gid; i < N_NODES; i += nthr) deg[i] = 0;
    for (int i = gid; i < (N_NODES * F) / 8; i += nthr) x2bf_one(i, x, xb);
    for (int i = gid; i < 131072; i += nthr)
        wsplit_one(i, Wl0, Wr0, Wl1, Wr1, Wl2, Wr2, Wl3, Wr3, wtbase);
    grid.sync();

    // ---- phase B: degree histogram ----
    for (int e = gid; e < N_EDGES; e += nthr) atomicAdd(&deg[dst[e]], 1);
    grid.sync();

    // ---- phase C1: per-block sums (blocks 0..195) ----
    if (blockIdx.x < NB_SCAN) {
        int i = blockIdx.x * 256 + t;
        int v = (i < N_NODES) ? deg[i] : 0;
        #pragma unroll
        for (int off = 32; off > 0; off >>= 1) v += __shfl_down(v, off, 64);
        if ((t & 63) == 0) s[t >> 6] = v;
        __syncthreads();
        if (t == 0) bsum[blockIdx.x] = s[0] + s[1] + s[2] + s[3];
    }
    grid.sync();

    // ---- phase C2: block 0 scans the 196 block sums (exclusive) ----
    if (blockIdx.x == 0) {
        int v = (t < NB_SCAN) ? bsum[t] : 0;
        s[t] = v;
        __syncthreads();
        for (int off = 1; off < 256; off <<= 1) {
            int xv  = s[t];
            int add = (t >= off) ? s[t - off] : 0;
            __syncthreads();
            s[t] = xv + add;
            __syncthreads();
        }
        bsum[t] = (t == 0) ? 0 : s[t - 1];
    }
    grid.sync();

    // ---- phase C3: local scan + apply ----
    if (blockIdx.x < NB_SCAN) {
        int i = blockIdx.x * 256 + t;
        int d = (i < N_NODES) ? deg[i] : 0;
        s[t] = d;
        __syncthreads();
        for (int off = 1; off < 256; off <<= 1) {
            int xv  = s[t];
            int add = (t >= off) ? s[t - off] : 0;
            __syncthreads();
            s[t] = xv + add;
            __syncthreads();
        }
        int excl = s[t] - d + bsum[blockIdx.x];
        if (i < N_NODES) {
            row_start[i] = excl;
            cursor[i]    = excl;
            inv_deg[i]   = 1.0f / fmaxf((float)d, 1.0f);
        }
    }
    if (gid == 0) row_start[N_NODES] = N_EDGES;
    grid.sync();

    // ---- phase D: CSR fill ----
    for (int e = gid; e < N_EDGES; e += nthr) {
        int p = atomicAdd(&cursor[dst[e]], 1);
        eidx[p] = src[e];
    }
}

// ---------------------------------------------------------------------------
// Fallback path (non-cooperative), identical semantics
__global__ void deg_int_kernel(const int* __restrict__ dst, int* __restrict__ deg) {
    int e = blockIdx.x * blockDim.x + threadIdx.x;
    if (e < N_EDGES) atomicAdd(&deg[dst[e]], 1);
}
__global__ __launch_bounds__(256) void x2bf_kernel(const float* __restrict__ x,
                                                   unsigned short* __restrict__ xb) {
    int i = blockIdx.x * 256 + threadIdx.x;
    if (i < (N_NODES * F) / 8) x2bf_one(i, x, xb);
}
__global__ __launch_bounds__(256) void bsum_kernel(const int* __restrict__ deg,
                                                   int* __restrict__ bsum) {
    int i = blockIdx.x * 256 + threadIdx.x;
    int v = (i < N_NODES) ? deg[i] : 0;
    #pragma unroll
    for (int off = 32; off > 0; off >>= 1) v += __shfl_down(v, off, 64);
    __shared__ int wsum[4];
    if ((threadIdx.x & 63) == 0) wsum[threadIdx.x >> 6] = v;
    __syncthreads();
    if (threadIdx.x == 0) bsum[blockIdx.x] = wsum[0] + wsum[1] + wsum[2] + wsum[3];
}
__global__ __launch_bounds__(256) void p2_kernel(
    int* __restrict__ bsum,
    const float* __restrict__ Wl0, const float* __restrict__ Wr0,
    const float* __restrict__ Wl1, const float* __restrict__ Wr1,
    const float* __restrict__ Wl2, const float* __restrict__ Wr2,
    const float* __restrict__ Wl3, const float* __restrict__ Wr3,
    short* __restrict__ wtbase)
{
    if (blockIdx.x == 0) {
        __shared__ int s[256];
        int t = threadIdx.x;
        int v = (t < NB_SCAN) ? bsum[t] : 0;
        s[t] = v;
        __syncthreads();
        for (int off = 1; off < 256; off <<= 1) {
            int x = s[t];
            int add = (t >= off) ? s[t - off] : 0;
            __syncthreads();
            s[t] = x + add;
            __syncthreads();
        }
        bsum[t] = (t == 0) ? 0 : s[t - 1];
    } else {
        int gt = (blockIdx.x - 1) * 256 + threadIdx.x;
        wsplit_one(gt, Wl0, Wr0, Wl1, Wr1, Wl2, Wr2, Wl3, Wr3, wtbase);
    }
}
__global__ __launch_bounds__(256) void scan_apply_kernel(
    const int* __restrict__ deg, const int* __restrict__ boff,
    int* __restrict__ row_start, int* __restrict__ cursor,
    float* __restrict__ inv_deg)
{
    __shared__ int s[256];
    int b = blockIdx.x, t = threadIdx.x;
    int i = b * 256 + t;
    int d = (i < N_NODES) ? deg[i] : 0;
    s[t] = d;
    __syncthreads();
    for (int off = 1; off < 256; off <<= 1) {
        int x = s[t];
        int add = (t >= off) ? s[t - off] : 0;
        __syncthreads();
        s[t] = x + add;
        __syncthreads();
    }
    int excl = s[t] - d + boff[b];
    if (i < N_NODES) {
        row_start[i] = excl;
        cursor[i]    = excl;
        inv_deg[i]   = 1.0f / fmaxf((float)d, 1.0f);
    }
    if (b == 0 && t == 0) row_start[N_NODES] = N_EDGES;
}
__global__ void fill_kernel(const int* __restrict__ src, const int* __restrict__ dst,
                            int* __restrict__ cursor, int* __restrict__ eidx) {
    int e = blockIdx.x * blockDim.x + threadIdx.x;
    if (e < N_EDGES) {
        int p = atomicAdd(&cursor[dst[e]], 1);
        eidx[p] = src[e];
    }
}

// ---------------------------------------------------------------------------
// Fused layer (bf16 h): gather-mean (f32 accum) -> split-bf16 MFMA -> relu.
// Self half of A is bf16-exact => its lo plane is zero and is skipped.
__global__ __launch_bounds__(512) void layer_kernel(
    const unsigned short* __restrict__ hb_in, const int* __restrict__ row_start,
    const int* __restrict__ eidx, const float* __restrict__ inv_deg,
    const short* __restrict__ wt_hi, const short* __restrict__ wt_lo,
    const float* __restrict__ b, unsigned short* __restrict__ hb_out)
{
    __shared__ short Ahi[MROWS][ASTRIDE];
    __shared__ short Alo[MROWS][ALSTRIDE];   // agg half only

    const int t    = threadIdx.x;
    const int base = blockIdx.x * MROWS;

    // ---- gather phase: thread = (row rr, 8-col group c8) ----
    {
        const int c8  = t & 15;
        const int rr  = t >> 4;          // 0..31
        const int row = base + rr;
        const bool v  = (row < N_NODES);

        int a0 = 0, na = 0;
        float sc = 0.0f;
        if (v) {
            a0 = row_start[row];
            na = row_start[row + 1] - a0;
            sc = inv_deg[row];
        }

        short8 selfv = {0,0,0,0,0,0,0,0};
        if (v) selfv = *(const short8*)(hb_in + (size_t)row * F + c8 * 8);

        float acc[8] = {0,0,0,0,0,0,0,0};
        for (int eo = 0; eo < na; eo += 8) {
            int   idx[8];
            float msk[8];
            #pragma unroll
            for (int u = 0; u < 8; ++u) {
                bool ok = (eo + u) < na;
                int  sl = ok ? a0 + eo + u : a0;
                int  ia = eidx[sl];
                idx[u] = ok ? ia : 0;
                msk[u] = ok ? 1.0f : 0.0f;
            }
            #pragma unroll
            for (int u = 0; u < 8; ++u) {
                short8 hv = *(const short8*)(hb_in + (size_t)idx[u] * F + c8 * 8);
                uint4_t uw = *(const uint4_t*)&hv;
                #pragma unroll
                for (int q = 0; q < 4; ++q) {
                    unsigned wq = uw[q];
                    float flo = __uint_as_float(wq << 16);
                    float fhi = __uint_as_float(wq & 0xFFFF0000u);
                    acc[2 * q]     = fmaf(flo, msk[u], acc[2 * q]);
                    acc[2 * q + 1] = fmaf(fhi, msk[u], acc[2 * q + 1]);
                }
            }
        }

        short8 h8, l8;
        #pragma unroll
        for (int k = 0; k < 8; ++k) {
            short h, l;
            split_bf16(acc[k] * sc, h, l);
            h8[k] = h; l8[k] = l;
        }
        *(short8*)&Ahi[rr][c8 * 8] = h8;
        *(short8*)&Alo[rr][c8 * 8] = l8;
        *(short8*)&Ahi[rr][F + c8 * 8] = selfv;
    }
    __syncthreads();

    // ---- MFMA phase: wave w owns cols [w*16, w*16+16) ----
    const int w    = t >> 6;         // 0..7
    const int lane = t & 63;
    const int m    = lane & 15;
    const int quad = lane >> 4;
    const int n0   = w * 16 + m;

    f32x4 acc0 = {0,0,0,0};          // rows 0..15
    f32x4 acc1 = {0,0,0,0};          // rows 16..31

    #pragma unroll
    for (int ks = 0; ks < 4; ++ks) {             // agg half: hi + lo planes
        const int ko = ks * 32 + quad * 8;
        short8 ah0 = *(const short8*)&Ahi[m][ko];
        short8 ah1 = *(const short8*)&Ahi[16 + m][ko];
        short8 al0 = *(const short8*)&Alo[m][ko];
        short8 al1 = *(const short8*)&Alo[16 + m][ko];
        short8 bh  = *(const short8*)&wt_hi[(size_t)n0 * 256 + ko];
        short8 bl  = *(const short8*)&wt_lo[(size_t)n0 * 256 + ko];

        acc0 = __builtin_amdgcn_mfma_f32_16x16x32_bf16(ah0, bh, acc0, 0, 0, 0);
        acc0 = __builtin_amdgcn_mfma_f32_16x16x32_bf16(ah0, bl, acc0, 0, 0, 0);
        acc0 = __builtin_amdgcn_mfma_f32_16x16x32_bf16(al0, bh, acc0, 0, 0, 0);

        acc1 = __builtin_amdgcn_mfma_f32_16x16x32_bf16(ah1, bh, acc1, 0, 0, 0);
        acc1 = __builtin_amdgcn_mfma_f32_16x16x32_bf16(ah1, bl, acc1, 0, 0, 0);
        acc1 = __builtin_amdgcn_mfma_f32_16x16x32_bf16(al1, bh, acc1, 0, 0, 0);
    }
    #pragma unroll
    for (int ks = 4; ks < 8; ++ks) {             // self half: lo plane of A == 0
        const int ko = ks * 32 + quad * 8;
        short8 ah0 = *(const short8*)&Ahi[m][ko];
        short8 ah1 = *(const short8*)&Ahi[16 + m][ko];
        short8 bh  = *(const short8*)&wt_hi[(size_t)n0 * 256 + ko];
        short8 bl  = *(const short8*)&wt_lo[(size_t)n0 * 256 + ko];

        acc0 = __builtin_amdgcn_mfma_f32_16x16x32_bf16(ah0, bh, acc0, 0, 0, 0);
        acc0 = __builtin_amdgcn_mfma_f32_16x16x32_bf16(ah0, bl, acc0, 0, 0, 0);

        acc1 = __builtin_amdgcn_mfma_f32_16x16x32_bf16(ah1, bh, acc1, 0, 0, 0);
        acc1 = __builtin_amdgcn_mfma_f32_16x16x32_bf16(ah1, bl, acc1, 0, 0, 0);
    }

    // ---- epilogue: C/D layout col=lane&15, row=quad*4+reg ----
    float bj = b[n0];
    #pragma unroll
    for (int reg = 0; reg < 4; ++reg) {
        int r0 = base + quad * 4 + reg;
        int r1 = r0 + 16;
        if (r0 < N_NODES)
            hb_out[(size_t)r0 * F + n0] = f2bf_rne(fmaxf(acc0[reg] + bj, 0.0f));
        if (r1 < N_NODES)
            hb_out[(size_t)r1 * F + n0] = f2bf_rne(fmaxf(acc1[reg] + bj, 0.0f));
    }
}

// ---------------------------------------------------------------------------
__global__ __launch_bounds__(128) void poolhead_kernel(
    const int* __restrict__ batch, const unsigned short* __restrict__ hb,
    const float* __restrict__ Wf1, const float* __restrict__ bf1,
    const float* __restrict__ Wf2, const float* __restrict__ bf2,
    float* __restrict__ out)
{
    int g = blockIdx.x;
    int j = threadIdx.x;
    int lo = 0, hi = N_NODES;
    while (lo < hi) { int m = (lo + hi) >> 1; if (batch[m] < g) lo = m + 1; else hi = m; }
    int start = lo;
    hi = N_NODES;
    while (lo < hi) { int m = (lo + hi) >> 1; if (batch[m] <= g) lo = m + 1; else hi = m; }
    int end = lo;

    float acc = 0.0f;
    int r = start;
    for (; r + 4 <= end; r += 4) {
        float v0 = __uint_as_float((unsigned)hb[(size_t)(r + 0) * F + j] << 16);
        float v1 = __uint_as_float((unsigned)hb[(size_t)(r + 1) * F + j] << 16);
        float v2 = __uint_as_float((unsigned)hb[(size_t)(r + 2) * F + j] << 16);
        float v3 = __uint_as_float((unsigned)hb[(size_t)(r + 3) * F + j] << 16);
        acc += (v0 + v1) + (v2 + v3);
    }
    for (; r < end; ++r)
        acc += __uint_as_float((unsigned)hb[(size_t)r * F + j] << 16);

    __shared__ float p[F];
    __shared__ float emb[F];
    p[j] = acc / fmaxf((float)(end - start), 1.0f);
    __syncthreads();
    float e = bf1[j];
    #pragma unroll 8
    for (int k = 0; k < F; ++k) e += p[k] * Wf1[k * F + j];
    emb[j] = e;
    __syncthreads();
    if (j < 2) {
        float o = bf2[j];
        for (int k = 0; k < F; ++k) o += emb[k] * Wf2[k * 2 + j];
        out[(size_t)g * 2 + j] = o;
    }
}

extern "C" void kernel_launch(void* const* d_in, const int* in_sizes, int n_in,
                              void* d_out, int out_size, void* d_ws, size_t ws_size,
                              hipStream_t stream) {
    const float* x     = (const float*)d_in[0];
    const int*   ei    = (const int*)d_in[1];
    const int*   src   = ei;
    const int*   dst   = ei + N_EDGES;
    const int*   batch = (const int*)d_in[2];
    const float* Wl0 = (const float*)d_in[4];
    const float* Wr0 = (const float*)d_in[5];
    const float* Wl1 = (const float*)d_in[7];
    const float* Wr1 = (const float*)d_in[8];
    const float* Wl2 = (const float*)d_in[10];
    const float* Wr2 = (const float*)d_in[11];
    const float* Wl3 = (const float*)d_in[13];
    const float* Wr3 = (const float*)d_in[14];
    const float* bb[4] = {(const float*)d_in[6],  (const float*)d_in[9],
                          (const float*)d_in[12], (const float*)d_in[15]};
    const float* Wf1 = (const float*)d_in[16];
    const float* bf1 = (const float*)d_in[17];
    const float* Wf2 = (const float*)d_in[18];
    const float* bf2 = (const float*)d_in[19];
    float* out = (float*)d_out;

    // workspace layout
    const size_t HSZ = (size_t)N_NODES * F;            // 6.4M elems
    unsigned short* XB  = (unsigned short*)d_ws;       // bf16 x
    unsigned short* HB0 = XB + HSZ;
    unsigned short* HB1 = HB0 + HSZ;
    float* inv_deg   = (float*)(HB1 + HSZ);            // N_NODES
    int*   row_start = (int*)(inv_deg + N_NODES);      // N_NODES+1
    int*   cursor    = row_start + N_NODES + 1;        // N_NODES
    int*   eidx      = cursor + N_NODES;               // N_EDGES
    int*   deg_i     = eidx + N_EDGES;                 // N_NODES
    int*   bsum      = deg_i + N_NODES;                // 256
    short* wtbase    = (short*)(bsum + 256);           // 4 x 65536 shorts

    // cooperative fused prep — 8 blocks/CU co-residency (12 VGPR, 1 KB LDS)
    void* args[] = {
        (void*)&src, (void*)&dst, (void*)&x,
        (void*)&Wl0, (void*)&Wr0, (void*)&Wl1, (void*)&Wr1,
        (void*)&Wl2, (void*)&Wr2, (void*)&Wl3, (void*)&Wr3,
        (void*)&wtbase, (void*)&XB, (void*)&deg_i, (void*)&bsum,
        (void*)&row_start, (void*)&cursor, (void*)&inv_deg, (void*)&eidx
    };
    hipError_t cerr = hipErrorUnknown;
    for (int nb : {2048, 1024, 512}) {
        cerr = hipLaunchCooperativeKernel(
            (const void*)prep_kernel, dim3(nb), dim3(256), args, 0, stream);
        if (cerr == hipSuccess) break;
    }
    if (cerr != hipSuccess) {
        // fallback: classic chain
        (void)hipMemsetAsync(deg_i, 0, N_NODES * sizeof(int), stream);
        deg_int_kernel<<<(N_EDGES + 255) / 256, 256, 0, stream>>>(dst, deg_i);
        bsum_kernel<<<NB_SCAN, 256, 0, stream>>>(deg_i, bsum);
        p2_kernel<<<513, 256, 0, stream>>>(bsum,
            Wl0, Wr0, Wl1, Wr1, Wl2, Wr2, Wl3, Wr3, wtbase);
        scan_apply_kernel<<<NB_SCAN, 256, 0, stream>>>(deg_i, bsum, row_start, cursor, inv_deg);
        fill_kernel<<<(N_EDGES + 255) / 256, 256, 0, stream>>>(src, dst, cursor, eidx);
        x2bf_kernel<<<(int)((HSZ / 8 + 255) / 256), 256, 0, stream>>>(x, XB);
    }

    const int layer_blocks = (N_NODES + MROWS - 1) / MROWS;  // 1563
    const unsigned short* hin = XB;
    unsigned short* buf[2] = {HB0, HB1};
    for (int l = 0; l < 4; ++l) {
        unsigned short* tgt = buf[l & 1];
        const short* whi = wtbase + (size_t)l * 65536;
        const short* wlo = whi + 32768;
        layer_kernel<<<layer_blocks, 512, 0, stream>>>(
            hin, row_start, eidx, inv_deg, whi, wlo, bb[l], tgt);
        hin = tgt;
    }

    poolhead_kernel<<<N_GRAPHS, 128, 0, stream>>>(batch, hin, Wf1, bf1, Wf2, bf2, out);
}

// Round 11
// 408.079 us; speedup vs baseline: 3.3650x; 3.3650x over previous
//
#include <hip/hip_runtime.h>

#define N_NODES   50000
#define N_EDGES   600000
#define F         128
#define N_GRAPHS  512
#define MROWS     32          // rows per block in layer kernel
#define ASTRIDE   264         // Ahi LDS row stride in shorts (16B-aligned)
#define ALSTRIDE  136         // Alo LDS row stride in shorts (agg half only)
#define NB_SCAN   196         // ceil(N_NODES/256)

typedef short          short8   __attribute__((ext_vector_type(8)));
typedef float          f32x4    __attribute__((ext_vector_type(4)));
typedef unsigned int   uint4_t  __attribute__((ext_vector_type(4)));

__device__ __forceinline__ void split_bf16(float v, short& hi, short& lo) {
    unsigned u  = __float_as_uint(v);
    unsigned hb = u & 0xFFFF0000u;
    hi = (short)(u >> 16);
    float rem = v - __uint_as_float(hb);
    lo = (short)(__float_as_uint(rem) >> 16);
}

// f32 -> bf16 round-to-nearest-even
__device__ __forceinline__ unsigned short f2bf_rne(float f) {
    unsigned u = __float_as_uint(f);
    u += 0x7FFFu + ((u >> 16) & 1u);
    return (unsigned short)(u >> 16);
}

// ---------------------------------------------------------------------------
// prepA: x->bf16, W transpose+split (4 layers), degree histogram.
// All three are independent; deg must be pre-zeroed (memset).
__global__ __launch_bounds__(256) void prepA_kernel(
    const float* __restrict__ x, unsigned short* __restrict__ xb,
    const float* __restrict__ Wl0, const float* __restrict__ Wr0,
    const float* __restrict__ Wl1, const float* __restrict__ Wr1,
    const float* __restrict__ Wl2, const float* __restrict__ Wr2,
    const float* __restrict__ Wl3, const float* __restrict__ Wr3,
    short* __restrict__ wtbase,
    const int* __restrict__ dst, int* __restrict__ deg)
{
    const int gid  = blockIdx.x * 256 + threadIdx.x;
    const int nthr = gridDim.x * 256;

    // x -> bf16 (8 elems per iteration)
    for (int i = gid; i < (N_NODES * F) / 8; i += nthr) {
        float4 a = ((const float4*)x)[2 * i];
        float4 b = ((const float4*)x)[2 * i + 1];
        short8 o;
        o[0] = (short)f2bf_rne(a.x); o[1] = (short)f2bf_rne(a.y);
        o[2] = (short)f2bf_rne(a.z); o[3] = (short)f2bf_rne(a.w);
        o[4] = (short)f2bf_rne(b.x); o[5] = (short)f2bf_rne(b.y);
        o[6] = (short)f2bf_rne(b.z); o[7] = (short)f2bf_rne(b.w);
        ((short8*)xb)[i] = o;
    }

    // W split: gt = l*32768 + n*256 + k
    for (int gt = gid; gt < 131072; gt += nthr) {
        int l = gt >> 15;
        int t = gt & 32767;
        const float* Wl; const float* Wr;
        switch (l) {
            case 0:  Wl = Wl0; Wr = Wr0; break;
            case 1:  Wl = Wl1; Wr = Wr1; break;
            case 2:  Wl = Wl2; Wr = Wr2; break;
            default: Wl = Wl3; Wr = Wr3; break;
        }
        int n = t >> 8, k = t & 255;
        float w = (k < F) ? Wl[k * F + n] : Wr[(k - F) * F + n];
        short h, lo;
        split_bf16(w, h, lo);
        short* hi_plane = wtbase + (size_t)l * 65536;
        hi_plane[t]         = h;
        hi_plane[32768 + t] = lo;
    }

    // degree histogram
    for (int e = gid; e < N_EDGES; e += nthr) atomicAdd(&deg[dst[e]], 1);
}

// ---- per-block sums of deg ----
__global__ __launch_bounds__(256) void bsum_kernel(const int* __restrict__ deg,
                                                   int* __restrict__ bsum) {
    int i = blockIdx.x * 256 + threadIdx.x;
    int v = (i < N_NODES) ? deg[i] : 0;
    #pragma unroll
    for (int off = 32; off > 0; off >>= 1) v += __shfl_down(v, off, 64);
    __shared__ int wsum[4];
    if ((threadIdx.x & 63) == 0) wsum[threadIdx.x >> 6] = v;
    __syncthreads();
    if (threadIdx.x == 0) bsum[blockIdx.x] = wsum[0] + wsum[1] + wsum[2] + wsum[3];
}

// ---- scan+apply: every block redundantly scans the 196 block sums (cheap),
//      then does its local 256-scan and writes row_start/cursor/inv_deg ----
__global__ __launch_bounds__(256) void scan_apply_kernel(
    const int* __restrict__ deg, const int* __restrict__ bsum,
    int* __restrict__ row_start, int* __restrict__ cursor,
    float* __restrict__ inv_deg)
{
    __shared__ int s[256];
    const int b = blockIdx.x, t = threadIdx.x;

    // redundant scan of block sums
    int v = (t < NB_SCAN) ? bsum[t] : 0;
    s[t] = v;
    __syncthreads();
    for (int off = 1; off < 256; off <<= 1) {
        int xv  = s[t];
        int add = (t >= off) ? s[t - off] : 0;
        __syncthreads();
        s[t] = xv + add;
        __syncthreads();
    }
    const int boff = (b == 0) ? 0 : s[b - 1];   // exclusive prefix for this block
    __syncthreads();

    // local scan
    int i = b * 256 + t;
    int d = (i < N_NODES) ? deg[i] : 0;
    s[t] = d;
    __syncthreads();
    for (int off = 1; off < 256; off <<= 1) {
        int xv  = s[t];
        int add = (t >= off) ? s[t - off] : 0;
        __syncthreads();
        s[t] = xv + add;
        __syncthreads();
    }
    int excl = s[t] - d + boff;
    if (i < N_NODES) {
        row_start[i] = excl;
        cursor[i]    = excl;
        inv_deg[i]   = 1.0f / fmaxf((float)d, 1.0f);
    }
    if (b == 0 && t == 0) row_start[N_NODES] = N_EDGES;
}

__global__ void fill_kernel(const int* __restrict__ src, const int* __restrict__ dst,
                            int* __restrict__ cursor, int* __restrict__ eidx) {
    int e = blockIdx.x * blockDim.x + threadIdx.x;
    if (e < N_EDGES) {
        int p = atomicAdd(&cursor[dst[e]], 1);
        eidx[p] = src[e];
    }
}

// ---------------------------------------------------------------------------
// Fused layer (bf16 h): gather-mean (f32 accum) -> split-bf16 MFMA -> relu.
// Self half of A is bf16-exact => its lo plane is zero and is skipped.
__global__ __launch_bounds__(512) void layer_kernel(
    const unsigned short* __restrict__ hb_in, const int* __restrict__ row_start,
    const int* __restrict__ eidx, const float* __restrict__ inv_deg,
    const short* __restrict__ wt_hi, const short* __restrict__ wt_lo,
    const float* __restrict__ b, unsigned short* __restrict__ hb_out)
{
    __shared__ short Ahi[MROWS][ASTRIDE];
    __shared__ short Alo[MROWS][ALSTRIDE];   // agg half only

    const int t    = threadIdx.x;
    const int base = blockIdx.x * MROWS;

    // ---- gather phase: thread = (row rr, 8-col group c8) ----
    {
        const int c8  = t & 15;
        const int rr  = t >> 4;          // 0..31
        const int row = base + rr;
        const bool v  = (row < N_NODES);

        int a0 = 0, na = 0;
        float sc = 0.0f;
        if (v) {
            a0 = row_start[row];
            na = row_start[row + 1] - a0;
            sc = inv_deg[row];
        }

        short8 selfv = {0,0,0,0,0,0,0,0};
        if (v) selfv = *(const short8*)(hb_in + (size_t)row * F + c8 * 8);

        float acc[8] = {0,0,0,0,0,0,0,0};
        for (int eo = 0; eo < na; eo += 8) {
            int   idx[8];
            float msk[8];
            #pragma unroll
            for (int u = 0; u < 8; ++u) {
                bool ok = (eo + u) < na;
                int  sl = ok ? a0 + eo + u : a0;
                int  ia = eidx[sl];
                idx[u] = ok ? ia : 0;
                msk[u] = ok ? 1.0f : 0.0f;
            }
            #pragma unroll
            for (int u = 0; u < 8; ++u) {
                short8 hv = *(const short8*)(hb_in + (size_t)idx[u] * F + c8 * 8);
                uint4_t uw = *(const uint4_t*)&hv;
                #pragma unroll
                for (int q = 0; q < 4; ++q) {
                    unsigned wq = uw[q];
                    float flo = __uint_as_float(wq << 16);
                    float fhi = __uint_as_float(wq & 0xFFFF0000u);
                    acc[2 * q]     = fmaf(flo, msk[u], acc[2 * q]);
                    acc[2 * q + 1] = fmaf(fhi, msk[u], acc[2 * q + 1]);
                }
            }
        }

        short8 h8, l8;
        #pragma unroll
        for (int k = 0; k < 8; ++k) {
            short h, l;
            split_bf16(acc[k] * sc, h, l);
            h8[k] = h; l8[k] = l;
        }
        *(short8*)&Ahi[rr][c8 * 8] = h8;
        *(short8*)&Alo[rr][c8 * 8] = l8;
        *(short8*)&Ahi[rr][F + c8 * 8] = selfv;
    }
    __syncthreads();

    // ---- MFMA phase: wave w owns cols [w*16, w*16+16) ----
    const int w    = t >> 6;         // 0..7
    const int lane = t & 63;
    const int m    = lane & 15;
    const int quad = lane >> 4;
    const int n0   = w * 16 + m;

    f32x4 acc0 = {0,0,0,0};          // rows 0..15
    f32x4 acc1 = {0,0,0,0};          // rows 16..31

    #pragma unroll
    for (int ks = 0; ks < 4; ++ks) {             // agg half: hi + lo planes
        const int ko = ks * 32 + quad * 8;
        short8 ah0 = *(const short8*)&Ahi[m][ko];
        short8 ah1 = *(const short8*)&Ahi[16 + m][ko];
        short8 al0 = *(const short8*)&Alo[m][ko];
        short8 al1 = *(const short8*)&Alo[16 + m][ko];
        short8 bh  = *(const short8*)&wt_hi[(size_t)n0 * 256 + ko];
        short8 bl  = *(const short8*)&wt_lo[(size_t)n0 * 256 + ko];

        acc0 = __builtin_amdgcn_mfma_f32_16x16x32_bf16(ah0, bh, acc0, 0, 0, 0);
        acc0 = __builtin_amdgcn_mfma_f32_16x16x32_bf16(ah0, bl, acc0, 0, 0, 0);
        acc0 = __builtin_amdgcn_mfma_f32_16x16x32_bf16(al0, bh, acc0, 0, 0, 0);

        acc1 = __builtin_amdgcn_mfma_f32_16x16x32_bf16(ah1, bh, acc1, 0, 0, 0);
        acc1 = __builtin_amdgcn_mfma_f32_16x16x32_bf16(ah1, bl, acc1, 0, 0, 0);
        acc1 = __builtin_amdgcn_mfma_f32_16x16x32_bf16(al1, bh, acc1, 0, 0, 0);
    }
    #pragma unroll
    for (int ks = 4; ks < 8; ++ks) {             // self half: lo plane of A == 0
        const int ko = ks * 32 + quad * 8;
        short8 ah0 = *(const short8*)&Ahi[m][ko];
        short8 ah1 = *(const short8*)&Ahi[16 + m][ko];
        short8 bh  = *(const short8*)&wt_hi[(size_t)n0 * 256 + ko];
        short8 bl  = *(const short8*)&wt_lo[(size_t)n0 * 256 + ko];

        acc0 = __builtin_amdgcn_mfma_f32_16x16x32_bf16(ah0, bh, acc0, 0, 0, 0);
        acc0 = __builtin_amdgcn_mfma_f32_16x16x32_bf16(ah0, bl, acc0, 0, 0, 0);

        acc1 = __builtin_amdgcn_mfma_f32_16x16x32_bf16(ah1, bh, acc1, 0, 0, 0);
        acc1 = __builtin_amdgcn_mfma_f32_16x16x32_bf16(ah1, bl, acc1, 0, 0, 0);
    }

    // ---- epilogue: C/D layout col=lane&15, row=quad*4+reg ----
    float bj = b[n0];
    #pragma unroll
    for (int reg = 0; reg < 4; ++reg) {
        int r0 = base + quad * 4 + reg;
        int r1 = r0 + 16;
        if (r0 < N_NODES)
            hb_out[(size_t)r0 * F + n0] = f2bf_rne(fmaxf(acc0[reg] + bj, 0.0f));
        if (r1 < N_NODES)
            hb_out[(size_t)r1 * F + n0] = f2bf_rne(fmaxf(acc1[reg] + bj, 0.0f));
    }
}

// ---------------------------------------------------------------------------
__global__ __launch_bounds__(128) void poolhead_kernel(
    const int* __restrict__ batch, const unsigned short* __restrict__ hb,
    const float* __restrict__ Wf1, const float* __restrict__ bf1,
    const float* __restrict__ Wf2, const float* __restrict__ bf2,
    float* __restrict__ out)
{
    int g = blockIdx.x;
    int j = threadIdx.x;
    int lo = 0, hi = N_NODES;
    while (lo < hi) { int m = (lo + hi) >> 1; if (batch[m] < g) lo = m + 1; else hi = m; }
    int start = lo;
    hi = N_NODES;
    while (lo < hi) { int m = (lo + hi) >> 1; if (batch[m] <= g) lo = m + 1; else hi = m; }
    int end = lo;

    float acc = 0.0f;
    int r = start;
    for (; r + 4 <= end; r += 4) {
        float v0 = __uint_as_float((unsigned)hb[(size_t)(r + 0) * F + j] << 16);
        float v1 = __uint_as_float((unsigned)hb[(size_t)(r + 1) * F + j] << 16);
        float v2 = __uint_as_float((unsigned)hb[(size_t)(r + 2) * F + j] << 16);
        float v3 = __uint_as_float((unsigned)hb[(size_t)(r + 3) * F + j] << 16);
        acc += (v0 + v1) + (v2 + v3);
    }
    for (; r < end; ++r)
        acc += __uint_as_float((unsigned)hb[(size_t)r * F + j] << 16);

    __shared__ float p[F];
    __shared__ float emb[F];
    p[j] = acc / fmaxf((float)(end - start), 1.0f);
    __syncthreads();
    float e = bf1[j];
    #pragma unroll 8
    for (int k = 0; k < F; ++k) e += p[k] * Wf1[k * F + j];
    emb[j] = e;
    __syncthreads();
    if (j < 2) {
        float o = bf2[j];
        for (int k = 0; k < F; ++k) o += emb[k] * Wf2[k * 2 + j];
        out[(size_t)g * 2 + j] = o;
    }
}

extern "C" void kernel_launch(void* const* d_in, const int* in_sizes, int n_in,
                              void* d_out, int out_size, void* d_ws, size_t ws_size,
                              hipStream_t stream) {
    const float* x     = (const float*)d_in[0];
    const int*   ei    = (const int*)d_in[1];
    const int*   src   = ei;
    const int*   dst   = ei + N_EDGES;
    const int*   batch = (const int*)d_in[2];
    const float* Wl0 = (const float*)d_in[4];
    const float* Wr0 = (const float*)d_in[5];
    const float* Wl1 = (const float*)d_in[7];
    const float* Wr1 = (const float*)d_in[8];
    const float* Wl2 = (const float*)d_in[10];
    const float* Wr2 = (const float*)d_in[11];
    const float* Wl3 = (const float*)d_in[13];
    const float* Wr3 = (const float*)d_in[14];
    const float* bb[4] = {(const float*)d_in[6],  (const float*)d_in[9],
                          (const float*)d_in[12], (const float*)d_in[15]};
    const float* Wf1 = (const float*)d_in[16];
    const float* bf1 = (const float*)d_in[17];
    const float* Wf2 = (const float*)d_in[18];
    const float* bf2 = (const float*)d_in[19];
    float* out = (float*)d_out;

    // workspace layout
    const size_t HSZ = (size_t)N_NODES * F;            // 6.4M elems
    unsigned short* XB  = (unsigned short*)d_ws;       // bf16 x
    unsigned short* HB0 = XB + HSZ;
    unsigned short* HB1 = HB0 + HSZ;
    float* inv_deg   = (float*)(HB1 + HSZ);            // N_NODES
    int*   row_start = (int*)(inv_deg + N_NODES);      // N_NODES+1
    int*   cursor    = row_start + N_NODES + 1;        // N_NODES
    int*   eidx      = cursor + N_NODES;               // N_EDGES
    int*   deg_i     = eidx + N_EDGES;                 // N_NODES (zeroed)
    int*   bsum      = deg_i + N_NODES;                // 256
    short* wtbase    = (short*)(bsum + 256);           // 4 x 65536 shorts

    (void)hipMemsetAsync(deg_i, 0, N_NODES * sizeof(int), stream);

    // CSR build + weight prep + x conversion (5 dispatches, no grid sync)
    prepA_kernel<<<1024, 256, 0, stream>>>(
        x, XB, Wl0, Wr0, Wl1, Wr1, Wl2, Wr2, Wl3, Wr3, wtbase, dst, deg_i);
    bsum_kernel<<<NB_SCAN, 256, 0, stream>>>(deg_i, bsum);
    scan_apply_kernel<<<NB_SCAN, 256, 0, stream>>>(deg_i, bsum, row_start, cursor, inv_deg);
    fill_kernel<<<(N_EDGES + 255) / 256, 256, 0, stream>>>(src, dst, cursor, eidx);

    const int layer_blocks = (N_NODES + MROWS - 1) / MROWS;  // 1563
    const unsigned short* hin = XB;
    unsigned short* buf[2] = {HB0, HB1};
    for (int l = 0; l < 4; ++l) {
        unsigned short* tgt = buf[l & 1];
        const short* whi = wtbase + (size_t)l * 65536;
        const short* wlo = whi + 32768;
        layer_kernel<<<layer_blocks, 512, 0, stream>>>(
            hin, row_start, eidx, inv_deg, whi, wlo, bb[l], tgt);
        hin = tgt;
    }

    poolhead_kernel<<<N_GRAPHS, 128, 0, stream>>>(batch, hin, Wf1, bf1, Wf2, bf2, out);
}